// Round 10
// baseline (1054.720 us; speedup 1.0000x reference)
//
#include <hip/hip_runtime.h>

// LSTM encoder B=1024,S=64,H=256 — v10: two-group pipeline, shuffle-cell,
// tagged coalesced exchange. 32 clusters x 8 WGs x 512 threads (cooperative).
// Cluster owns 32 batches (2 groups of 16); WG owns 32 h-dims; each wave owns
// 4 dims x {i,f,g,o} = 16 gate rows in registers (wf[16], pinned). Per phase:
// one lgkmcnt-only barrier; MFMA M=16 K=512; 4x4 shfl transpose -> in-lane
// cell; publish+gather via u32{tag|bf16} agent atomics (fire-and-forget,
// self-validating). Group A's exchange RTT hides under group B's phase.

typedef __attribute__((ext_vector_type(8))) short short8;
typedef __attribute__((ext_vector_type(4))) float f32x4;
typedef unsigned long long u64;
typedef unsigned int u32;
typedef unsigned short u16;

#define B_ 1024
#define S_ 64
#define H_ 256
#define G_ 1024
#define KW 512
#define OUTN (B_*S_*H_)
#define APITCH 522        // u16 pitch (261 dwords, odd/2: measured-best conflicts)
#define NCL 32
#define CWG 8
#define B256 (B_*256)     // u32 slots per parity buffer

__device__ __forceinline__ u16 f2bf(float f){
    u32 u = __builtin_bit_cast(u32, f);
    u = (u + 0x7fffu + ((u >> 16) & 1u)) >> 16;   // RNE
    return (u16)u;
}
__device__ __forceinline__ float sigm(float v){ return 1.0f/(1.0f + __expf(-v)); }
__device__ __forceinline__ float tanh_(float v){ return 2.0f/(1.0f + __expf(-2.0f*v)) - 1.0f; }

// raw workgroup barrier: waits LDS ops only (no vmcnt drain)
__device__ __forceinline__ void wg_barrier_lds(){
    asm volatile("s_waitcnt lgkmcnt(0)" ::: "memory");
    __builtin_amdgcn_sched_barrier(0);
    __builtin_amdgcn_s_barrier();
    __builtin_amdgcn_sched_barrier(0);
}

__global__ __launch_bounds__(256) void prep_kernel(const float* __restrict__ Wih,
        const float* __restrict__ Whh, const float* __restrict__ bih,
        const float* __restrict__ bhh, const float* __restrict__ h0,
        u16* __restrict__ Wc, float* __restrict__ bias, u32* __restrict__ hq){
    int idx = blockIdx.x*256 + threadIdx.x;
    if (idx < G_*KW){
        int g = idx >> 9, k = idx & 511;
        float v = (k < H_) ? Wih[g*H_ + k] : Whh[g*H_ + (k - H_)];
        Wc[idx] = f2bf(v);
    }
    if (idx < G_) bias[idx] = bih[idx] + bhh[idx];
    if (idx < B256){
        hq[idx] = (u32)f2bf(h0[idx]);        // parity 0: h(0), tag 0
        hq[B256 + idx] = 0xFFFF0000u;        // parity 1: stale tag
    }
}

__global__ __launch_bounds__(512, 2) void lstm_kernel(
        const float* __restrict__ x, const float* __restrict__ c0,
        const u16* __restrict__ Wc, const float* __restrict__ bias,
        u32* hq, float* __restrict__ out){
    __shared__ u16 At0[16*APITCH];   // group 0: [batch 0..15][k: 0..255=x, 256..511=h]
    __shared__ u16 At1[16*APITCH];   // group 1

    const int tid  = threadIdx.x;
    const int lane = tid & 63;
    const int w    = tid >> 6;
    const int nl   = lane & 15, kg = lane >> 4;
    const int bid  = blockIdx.x;
    const int cl   = bid & (NCL-1);
    const int j    = bid >> 5;        // wg-in-cluster 0..7
    const int b0   = cl * 32;
    const int d0   = j * 32;

    // ---- wave's 16 gate rows: g = type*256 + dim, type=nl>>2, dim=d0+4w+(nl&3) ----
    const int dpart    = d0 + 4*w + (nl & 3);
    const int grow_idx = (nl >> 2)*256 + dpart;
    short8 wf[16];
    {
        const u16* wp = Wc + (size_t)grow_idx*KW + kg*8;
        #pragma unroll
        for (int kf = 0; kf < 16; ++kf) wf[kf] = *(const short8*)(wp + kf*32);
    }
    #pragma unroll
    for (int kf = 0; kf < 16; ++kf) asm volatile("" : "+v"(wf[kf]));  // pin
    const float bias_l = bias[grow_idx];

    // ---- cell slot: batch bcell (in-group), dim dcell (absolute) ----
    const int bcell = kg*4 + (nl >> 2);
    const int dcell = dpart;
    float c_0 = c0[(size_t)(b0 + bcell)*H_ + dcell];
    float c_1 = c0[(size_t)(b0 + 16 + bcell)*H_ + dcell];

    // ---- prologue: stage x(0)+h(0) both groups; prefetch x(1) ----
    f32x4 xa_0, xb_0, xa_1, xb_1;
    {
        const int bx = tid >> 5, cx = tid & 31;
        #pragma unroll
        for (int G2 = 0; G2 < 2; ++G2){
            u16* Atg = G2 ? At1 : At0;
            const float* xp = x + ((size_t)(b0 + 16*G2 + bx)*S_ + 0)*H_ + cx*8;
            f32x4 a = *(const f32x4*)xp, b = *(const f32x4*)(xp+4);
            u16 tx[8];
            tx[0]=f2bf(a[0]); tx[1]=f2bf(a[1]); tx[2]=f2bf(a[2]); tx[3]=f2bf(a[3]);
            tx[4]=f2bf(b[0]); tx[5]=f2bf(b[1]); tx[6]=f2bf(b[2]); tx[7]=f2bf(b[3]);
            *(short8*)(Atg + bx*APITCH + cx*8) = *(const short8*)tx;
            const u32* hb = hq + ((size_t)(b0 + 16*G2) << 8);
            #pragma unroll
            for (int i = 0; i < 8; ++i){
                int f = i*512 + tid;
                u32 v = hb[f];
                Atg[(f >> 8)*APITCH + H_ + (f & 255)] = (u16)(v & 0xFFFFu);
            }
        }
        const float* xp0 = x + ((size_t)(b0 + (tid>>5))*S_ + 1)*H_ + (tid&31)*8;
        const float* xp1 = x + ((size_t)(b0 + 16 + (tid>>5))*S_ + 1)*H_ + (tid&31)*8;
        xa_0 = *(const f32x4*)xp0; xb_0 = *(const f32x4*)(xp0+4);
        xa_1 = *(const f32x4*)xp1; xb_1 = *(const f32x4*)(xp1+4);
    }
    __syncthreads();

    u32 gv_0[8], gv_1[8];
    #pragma unroll
    for (int i = 0; i < 8; ++i){ gv_0[i] = 0xFFFF0000u; gv_1[i] = 0xFFFF0000u; }

#define PHASE(GL, CREG, XA, XB, GV, ATG) do {                                  \
    const size_t bbase = (size_t)(b0 + 16*(GL)) << 8;                          \
    if (s > 0){                                                                \
        const u32 want = (u32)s;                                               \
        const u32* gb = hq + (size_t)(s & 1)*B256 + bbase;                     \
        int guard = 0;                                                         \
        for (;;){                                                              \
            bool ok = true;                                                    \
            _Pragma("unroll")                                                  \
            for (int i = 0; i < 8; ++i) ok = ok && ((GV[i] >> 16) == want);    \
            if (__all((int)ok)) break;                                         \
            if (++guard > 8192) break;   /* fail loud, never hang */           \
            _Pragma("unroll")                                                  \
            for (int i = 0; i < 8; ++i)                                        \
                if ((GV[i] >> 16) != want)                                     \
                    GV[i] = __hip_atomic_load(gb + i*512 + tid,                \
                            __ATOMIC_RELAXED, __HIP_MEMORY_SCOPE_AGENT);       \
        }                                                                      \
        _Pragma("unroll")                                                      \
        for (int i = 0; i < 8; ++i){                                           \
            int f = i*512 + tid;                                               \
            ATG[(f >> 8)*APITCH + H_ + (f & 255)] = (u16)(GV[i] & 0xFFFFu);    \
        }                                                                      \
        u16 tx[8];                                                             \
        tx[0]=f2bf(XA[0]); tx[1]=f2bf(XA[1]); tx[2]=f2bf(XA[2]); tx[3]=f2bf(XA[3]); \
        tx[4]=f2bf(XB[0]); tx[5]=f2bf(XB[1]); tx[6]=f2bf(XB[2]); tx[7]=f2bf(XB[3]); \
        *(short8*)(ATG + (tid>>5)*APITCH + (tid&31)*8) = *(const short8*)tx;   \
    }                                                                          \
    wg_barrier_lds();                                                          \
    f32x4 acc_e = (f32x4){bias_l, bias_l, bias_l, bias_l};                     \
    f32x4 acc_o = (f32x4){0.f, 0.f, 0.f, 0.f};                                 \
    {                                                                          \
        const u16* ar = ATG + nl*APITCH + kg*8;                                \
        _Pragma("unroll")                                                      \
        for (int kf = 0; kf < 16; kf += 2){                                    \
            short8 a0 = *(const short8*)(ar + kf*32);                          \
            short8 a1 = *(const short8*)(ar + (kf+1)*32);                      \
            acc_e = __builtin_amdgcn_mfma_f32_16x16x32_bf16(a0, wf[kf],   acc_e, 0,0,0); \
            acc_o = __builtin_amdgcn_mfma_f32_16x16x32_bf16(a1, wf[kf+1], acc_o, 0,0,0); \
        }                                                                      \
    }                                                                          \
    float v0 = acc_e[0]+acc_o[0], v1 = acc_e[1]+acc_o[1];                      \
    float v2 = acc_e[2]+acc_o[2], v3 = acc_e[3]+acc_o[3];                      \
    {   /* 4x4 transpose: lane bits[3:2] <-> reg index */                      \
        bool hA = (lane >> 2) & 1;                                             \
        float sA = hA ? v0 : v1; float rA = __shfl_xor(sA, 4);                 \
        if (hA) v0 = rA; else v1 = rA;                                         \
        float sB = hA ? v2 : v3; float rB = __shfl_xor(sB, 4);                 \
        if (hA) v2 = rB; else v3 = rB;                                         \
        bool hB = (lane >> 3) & 1;                                             \
        float sC = hB ? v0 : v2; float rC = __shfl_xor(sC, 8);                 \
        if (hB) v0 = rC; else v2 = rC;                                         \
        float sD = hB ? v1 : v3; float rD = __shfl_xor(sD, 8);                 \
        if (hB) v1 = rD; else v3 = rD;                                         \
    }                                                                          \
    float cn = sigm(v1)*CREG + sigm(v0)*tanh_(v2);                             \
    float hn = sigm(v3)*tanh_(cn);                                             \
    CREG = cn;                                                                 \
    {                                                                          \
        size_t ob = ((size_t)(b0 + 16*(GL) + bcell)*S_ + s)*H_ + dcell;        \
        if (s < S_-1){                                                         \
            u32 pv = ((u32)(s+1) << 16) | (u32)f2bf(hn);                       \
            __hip_atomic_store(hq + (size_t)((s+1)&1)*B256 + bbase             \
                               + ((size_t)bcell << 8) + dcell, pv,             \
                               __ATOMIC_RELAXED, __HIP_MEMORY_SCOPE_AGENT);    \
            const u32* gb2 = hq + (size_t)((s+1)&1)*B256 + bbase;              \
            _Pragma("unroll")                                                  \
            for (int i = 0; i < 8; ++i)                                        \
                GV[i] = __hip_atomic_load(gb2 + i*512 + tid,                   \
                        __ATOMIC_RELAXED, __HIP_MEMORY_SCOPE_AGENT);           \
        }                                                                      \
        out[ob] = hn; out[OUTN + ob] = hn;                                     \
        if (s + 1 < S_){                                                       \
            const float* xp = x + ((size_t)(b0 + 16*(GL) + (tid>>5))*S_        \
                              + (s+1))*H_ + (tid&31)*8;                        \
            XA = *(const f32x4*)xp; XB = *(const f32x4*)(xp+4);                \
        }                                                                      \
    }                                                                          \
} while(0)

    #pragma unroll 1
    for (int s = 0; s < S_; ++s){
        PHASE(0, c_0, xa_0, xb_0, gv_0, At0);
        PHASE(1, c_1, xa_1, xb_1, gv_1, At1);
    }
#undef PHASE
}

extern "C" void kernel_launch(void* const* d_in, const int* in_sizes, int n_in,
                              void* d_out, int out_size, void* d_ws, size_t ws_size,
                              hipStream_t stream){
    const float* x   = (const float*)d_in[0];
    const float* h0  = (const float*)d_in[1];
    const float* c0  = (const float*)d_in[2];
    const float* Wih = (const float*)d_in[3];
    const float* Whh = (const float*)d_in[4];
    const float* bih = (const float*)d_in[5];
    const float* bhh = (const float*)d_in[6];

    u16*   Wc   = (u16*)d_ws;                          // 1 MB @ 0
    float* bias = (float*)((char*)d_ws + 0x100000);    // 4 KB
    u32*   hq   = (u32*)((char*)d_ws + 0x110000);      // 2 MB tagged h (2 parities)
    float* outp = (float*)d_out;

    prep_kernel<<<(G_*KW + 255)/256, 256, 0, stream>>>(Wih, Whh, bih, bhh, h0, Wc, bias, hq);

    void* args[] = {(void*)&x, (void*)&c0, (void*)&Wc, (void*)&bias,
                    (void*)&hq, (void*)&outp};
    hipLaunchCooperativeKernel((void*)lstm_kernel, dim3(NCL*CWG), dim3(512), args, 0, stream);
}

// Round 12
// 434.833 us; speedup vs baseline: 2.4256x; 2.4256x over previous
//
#include <hip/hip_runtime.h>

// LSTM encoder B=1024,S=64,H=256 — v12: v11 (no cross-WG exchange) + race fix
// + fp16 xg intermediate.
// Phase 1: xg = x@Wih^T + bias as GEMM, output FP16 packed INTO d_out
//   (gates i,f -> outputs(b,s) bytes; g,o -> hiddens(b,s) bytes).
// Phase 2: 256 WGs x 512 thr, each owns 4 batches, FULL H. W_hh resident:
//   6/8 in VGPRs (192/thread, pinned), 2/8 in LDS (128 KB). Per step: MFMA
//   (K=256) -> mid LDS-barrier (fixes v11 race: all MFMA reads drain before
//   h writeback) -> cell -> overwrite d_out slot with h. No inter-WG traffic.

typedef __attribute__((ext_vector_type(8))) short short8;
typedef __attribute__((ext_vector_type(4))) float f32x4;
typedef unsigned long long u64;
typedef unsigned int u32;
typedef unsigned short u16;

#define B_ 1024
#define S_ 64
#define H_ 256
#define G_ 1024
#define OUTN (B_*S_*H_)    // f32 elems per output tensor
#define APR 266            // recur At pitch (u16): 133 dwords, odd -> spread banks

__device__ __forceinline__ u16 f2bf(float f){
    u32 u = __builtin_bit_cast(u32, f);
    u = (u + 0x7fffu + ((u >> 16) & 1u)) >> 16;   // RNE
    return (u16)u;
}
__device__ __forceinline__ u16 f2h(float f){
    _Float16 h = (_Float16)f;                     // v_cvt_f16_f32, RNE
    return __builtin_bit_cast(u16, h);
}
__device__ __forceinline__ float h2f(u16 v){
    _Float16 h = __builtin_bit_cast(_Float16, v);
    return (float)h;
}
__device__ __forceinline__ float sigm(float v){ return 1.0f/(1.0f + __expf(-v)); }
__device__ __forceinline__ float tanh_(float v){ return 2.0f/(1.0f + __expf(-2.0f*v)) - 1.0f; }

__device__ __forceinline__ void gload_lds16(const void* g, void* l){
    __builtin_amdgcn_global_load_lds(
        (const __attribute__((address_space(1))) unsigned int*)g,
        (__attribute__((address_space(3))) unsigned int*)l, 16, 0, 0);
}
// LDS-only barrier (no vmcnt drain)
__device__ __forceinline__ void wg_barrier_lds(){
    asm volatile("s_waitcnt lgkmcnt(0)" ::: "memory");
    __builtin_amdgcn_sched_barrier(0);
    __builtin_amdgcn_s_barrier();
    __builtin_amdgcn_sched_barrier(0);
}

// ---------------- prep: weight conversion / fragment packing ----------------
__global__ __launch_bounds__(256) void prep_kernel(const float* __restrict__ Wih,
        const float* __restrict__ Whh, const float* __restrict__ bih,
        const float* __restrict__ bhh, u16* __restrict__ WhhF,
        u16* __restrict__ WihS, float* __restrict__ biasc){
    int idx = blockIdx.x*256 + threadIdx.x;          // 262144 threads
    if (idx < 262144){
        // Whh fragment: f = ((w*8+t)*8+kf)*64+lane; t=typ*2+half;
        // row = typ*256 + w*32 + half*16 + nl; k = kf*32 + kg*8 + e
        int e  = idx & 7, f = idx >> 3;
        int lane = f & 63, kf = (f >> 6) & 7, t = (f >> 9) & 7, w = f >> 12;
        int nl = lane & 15, kg = lane >> 4;
        int typ = t >> 1, half = t & 1;
        int row = typ*256 + w*32 + half*16 + nl;
        int k   = kf*32 + kg*8 + e;
        WhhF[idx] = f2bf(Whh[row*H_ + k]);
        // Wih swizzled [tn][kb] tiles of [128 n][64 k], byte within tile =
        // (n*128 + k*2) ^ ((n&7)<<4)
        int g2 = idx >> 8, k2 = idx & 255;
        int tn = g2 >> 7, n = g2 & 127, kb = k2 >> 6, kl = k2 & 63;
        int lb = (n*128 + kl*2) ^ ((n & 7) << 4);
        WihS[(size_t)(tn*4 + kb)*8192 + (lb >> 1)] = f2bf(Wih[g2*H_ + k2]);
    }
    if (idx < G_) biasc[idx] = bih[idx] + bhh[idx];
}

// ---------------- phase 1: xg GEMM -> fp16 into d_out ----------------
__global__ __launch_bounds__(256, 2) void gemm_kernel(const float* __restrict__ x,
        const u16* __restrict__ WihS, const float* __restrict__ biasc,
        u16* __restrict__ outu){
    __shared__ u16 As[2][128*72];    // [m][k] pitch 72
    __shared__ u16 Bs[2][128*64];    // [n][k] linear, pre-swizzled content

    const int tid = threadIdx.x, lane = tid & 63, w = tid >> 6;
    const int wm = w >> 1, wn = w & 1, nl = lane & 15, kg = lane >> 4;
    const int bid = blockIdx.x;
    const int m0 = (bid >> 3)*128, n0 = (bid & 7)*128;

    f32x4 acc[4][4];
    #pragma unroll
    for (int nt = 0; nt < 4; ++nt){
        float bq = biasc[n0 + wn*64 + nt*16 + nl];
        #pragma unroll
        for (int mt = 0; mt < 4; ++mt)
            acc[mt][nt] = (f32x4){bq, bq, bq, bq};
    }

    const int ar = tid >> 1, ah = tid & 1;    // A staging: row, 32-col half
    f32x4 xa[8];
    {
        const float* xp = x + (size_t)(m0 + ar)*H_ + ah*32;
        #pragma unroll
        for (int q = 0; q < 8; ++q) xa[q] = *(const f32x4*)(xp + q*4);
        u16 tmp[32];
        #pragma unroll
        for (int q = 0; q < 32; ++q) tmp[q] = f2bf(xa[q>>2][q&3]);
        #pragma unroll
        for (int q = 0; q < 4; ++q)
            *(short8*)(&As[0][ar*72 + ah*32 + q*8]) = *(const short8*)(tmp + q*8);
        const char* src = (const char*)(WihS + (size_t)((bid & 7)*4 + 0)*8192);
        #pragma unroll
        for (int i = 0; i < 4; ++i){
            int off = (w*4 + i)*1024;
            gload_lds16(src + off + lane*16, (char*)&Bs[0][0] + off);
        }
    }
    __syncthreads();

    #pragma unroll 1
    for (int kb = 0; kb < 4; ++kb){
        const int buf = kb & 1;
        if (kb < 3){
            const float* xp = x + (size_t)(m0 + ar)*H_ + (kb+1)*64 + ah*32;
            #pragma unroll
            for (int q = 0; q < 8; ++q) xa[q] = *(const f32x4*)(xp + q*4);
            const char* src = (const char*)(WihS + (size_t)((bid & 7)*4 + kb + 1)*8192);
            #pragma unroll
            for (int i = 0; i < 4; ++i){
                int off = (w*4 + i)*1024;
                gload_lds16(src + off + lane*16, (char*)&Bs[buf^1][0] + off);
            }
        }
        #pragma unroll
        for (int kf = 0; kf < 2; ++kf){
            short8 av[4], bv[4];
            #pragma unroll
            for (int mt = 0; mt < 4; ++mt)
                av[mt] = *(const short8*)(&As[buf][(wm*64 + mt*16 + nl)*72 + kf*32 + kg*8]);
            #pragma unroll
            for (int nt = 0; nt < 4; ++nt){
                int nloc = wn*64 + nt*16 + nl;
                int byte = (nloc*128 + kf*64 + kg*16) ^ ((nl & 7) << 4);
                bv[nt] = *(const short8*)((const char*)&Bs[buf][0] + byte);
            }
            #pragma unroll
            for (int mt = 0; mt < 4; ++mt)
                #pragma unroll
                for (int nt = 0; nt < 4; ++nt)
                    acc[mt][nt] = __builtin_amdgcn_mfma_f32_16x16x32_bf16(
                                      av[mt], bv[nt], acc[mt][nt], 0, 0, 0);
        }
        if (kb < 3){
            u16 tmp[32];
            #pragma unroll
            for (int q = 0; q < 32; ++q) tmp[q] = f2bf(xa[q>>2][q&3]);
            #pragma unroll
            for (int q = 0; q < 4; ++q)
                *(short8*)(&As[buf^1][ar*72 + ah*32 + q*8]) = *(const short8*)(tmp + q*8);
        }
        __syncthreads();
    }

    // epilogue: fp16 scatter into the two d_out regions
    #pragma unroll
    for (int mt = 0; mt < 4; ++mt)
        #pragma unroll
        for (int nt = 0; nt < 4; ++nt){
            int g = n0 + wn*64 + nt*16 + nl;
            size_t rb = (g < 512) ? 0 : (size_t)OUTN*2;
            size_t base = rb + (size_t)(m0 + wm*64 + mt*16 + kg*4)*512 + (g & 511);
            #pragma unroll
            for (int j = 0; j < 4; ++j)
                outu[base + (size_t)j*512] = f2h(acc[mt][nt][j]);
        }
}

// ---------------- phase 2: recurrence, zero inter-WG traffic ----------------
__global__ __launch_bounds__(512, 2) void recur_kernel(const u16* __restrict__ WhhF,
        const float* __restrict__ h0, const float* __restrict__ c0,
        float* __restrict__ out){
    __shared__ u16 WL[65536];        // 128 KB: Whh typ-3 tiles, frag-ordered
    __shared__ u16 At[16*APR];       // h tile [16][APR] (rows 0..3 real)
    __shared__ u16 xgl[2][4][1024];  // xg (fp16) double buffer [batch][gate]

    const int tid = threadIdx.x, lane = tid & 63, w = tid >> 6;
    const int nl = lane & 15, kg = lane >> 4;
    const int b0 = blockIdx.x * 4;
    u16* outu = (u16*)out;

    // ---- W_hh: 6 tiles (typ 0..2) in VGPRs, 2 tiles (typ 3) in LDS ----
    short8 wf[6][8];                 // 192 VGPRs
    #pragma unroll
    for (int t = 0; t < 6; ++t)
        #pragma unroll
        for (int kf = 0; kf < 8; ++kf)
            wf[t][kf] = *(const short8*)(WhhF + ((size_t)((w*8 + t)*8 + kf)*64 + lane)*8);
    #pragma unroll
    for (int t = 0; t < 6; ++t)
        #pragma unroll
        for (int kf = 0; kf < 8; ++kf)
            asm volatile("" : "+v"(wf[t][kf]));   // pin
    #pragma unroll
    for (int t = 6; t < 8; ++t)
        #pragma unroll
        for (int kf = 0; kf < 8; ++kf){
            int db = ((w*2 + (t-6))*8 + kf)*1024;
            const char* src = (const char*)WhhF + ((size_t)((w*8 + t)*8 + kf)*64)*16 + lane*16;
            gload_lds16(src, (char*)WL + db);
        }

    // ---- init LDS h-tile (+ zero pad rows), xg(0) ----
    for (int i = tid; i < 1024; i += 512){          // rows 0..3 = h0
        int j = i >> 8, d = i & 255;
        At[j*APR + d] = f2bf(h0[(size_t)(b0 + j)*H_ + d]);
    }
    for (int i = 4*APR + tid; i < 16*APR; i += 512) // rows 4..15 = 0 (+pads)
        At[i] = 0;
    {
        int jb = w >> 1, rg = w & 1;
        const char* src = (const char*)outu
            + ((rg ? (size_t)OUTN*2 : 0) + ((size_t)(b0 + jb)*S_ + 0)*512)*2 + lane*16;
        gload_lds16(src, (char*)xgl + jb*2048 + rg*1024);
    }
    float c_[8], h_[8];
    #pragma unroll
    for (int j = 0; j < 4; ++j)
        #pragma unroll
        for (int hf = 0; hf < 2; ++hf)
            c_[j*2 + hf] = c0[(size_t)(b0 + j)*H_ + 32*w + 16*hf + nl];
    __syncthreads();

    #pragma unroll 1
    for (int s = 0; s < S_; ++s){
        const int buf = s & 1;
        if (s < S_-1){   // prefetch xg(s+1) — lands under this step's compute
            int jb = w >> 1, rg = w & 1;
            const char* src = (const char*)outu
                + ((rg ? (size_t)OUTN*2 : 0) + ((size_t)(b0 + jb)*S_ + s + 1)*512)*2 + lane*16;
            gload_lds16(src, (char*)xgl + (buf^1)*8192 + jb*2048 + rg*1024);
        }
        #pragma unroll
        for (int hf = 0; hf < 2; ++hf){
            f32x4 ac[4];
            #pragma unroll
            for (int typ = 0; typ < 4; ++typ){
                #pragma unroll
                for (int j = 0; j < 4; ++j){
                    float v = 0.0f;
                    if (kg == 0)
                        v = h2f(xgl[buf][j][typ*256 + 32*w + 16*hf + nl]);
                    ac[typ][j] = v;
                }
            }
            #pragma unroll
            for (int kf = 0; kf < 8; ++kf){
                short8 av = *(const short8*)(At + nl*APR + kf*32 + kg*8);
                short8 bl = *(const short8*)((const char*)WL + ((w*2 + hf)*8 + kf)*1024 + lane*16);
                ac[0] = __builtin_amdgcn_mfma_f32_16x16x32_bf16(av, wf[0 + hf][kf], ac[0], 0, 0, 0);
                ac[1] = __builtin_amdgcn_mfma_f32_16x16x32_bf16(av, wf[2 + hf][kf], ac[1], 0, 0, 0);
                ac[2] = __builtin_amdgcn_mfma_f32_16x16x32_bf16(av, wf[4 + hf][kf], ac[2], 0, 0, 0);
                ac[3] = __builtin_amdgcn_mfma_f32_16x16x32_bf16(av, bl,             ac[3], 0, 0, 0);
            }
            if (kg == 0){
                #pragma unroll
                for (int j = 0; j < 4; ++j){
                    float iv = ac[0][j], fv = ac[1][j], gv = ac[2][j], ov = ac[3][j];
                    int slot = j*2 + hf;
                    float cn = sigm(fv)*c_[slot] + sigm(iv)*tanh_(gv);
                    float hn = sigm(ov)*tanh_(cn);
                    c_[slot] = cn; h_[slot] = hn;
                }
            }
        }
        // RACE FIX: all waves' MFMA ds_reads of At complete before overwrite
        wg_barrier_lds();

        if (kg == 0){
            #pragma unroll
            for (int j = 0; j < 4; ++j)
                #pragma unroll
                for (int hf = 0; hf < 2; ++hf){
                    int d = 32*w + 16*hf + nl;
                    float hn = h_[j*2 + hf];
                    At[j*APR + d] = f2bf(hn);
                    size_t o = ((size_t)(b0 + j)*S_ + s)*H_ + d;
                    out[o] = hn;
                    out[(size_t)OUTN + o] = hn;
                }
        }
        __syncthreads();   // At writes + xg prefetch drained before next step
    }
}

extern "C" void kernel_launch(void* const* d_in, const int* in_sizes, int n_in,
                              void* d_out, int out_size, void* d_ws, size_t ws_size,
                              hipStream_t stream){
    const float* x   = (const float*)d_in[0];
    const float* h0  = (const float*)d_in[1];
    const float* c0  = (const float*)d_in[2];
    const float* Wih = (const float*)d_in[3];
    const float* Whh = (const float*)d_in[4];
    const float* bih = (const float*)d_in[5];
    const float* bhh = (const float*)d_in[6];

    u16*   WhhF  = (u16*)d_ws;                        // 512 KB @ 0
    u16*   WihS  = (u16*)((char*)d_ws + 0x80000);     // 512 KB
    float* biasc = (float*)((char*)d_ws + 0x100000);  // 4 KB

    prep_kernel<<<1024, 256, 0, stream>>>(Wih, Whh, bih, bhh, WhhF, WihS, biasc);
    gemm_kernel<<<4096, 256, 0, stream>>>(x, WihS, biasc, (u16*)d_out);
    recur_kernel<<<256, 512, 0, stream>>>(WhhF, h0, c0, (float*)d_out);
}